// Round 1
// baseline (671.897 us; speedup 1.0000x reference)
//
#include <hip/hip_runtime.h>

#define NSEQ 2048
#define KDIM 1024
#define DH   64
#define NS   8
#define NR   2

// ================= Kernel 1: fused projection GEMM =================
// C[4096 x 1664] = x[4096 x 1024] @ concat(Wsq, Wsk, Wrq, Wrv)
// scattered into SQ/SK/RQ [b][s][n][64] and V [b][n][128].
// BM=128, BN=64, BK=16, 256 threads, 8x4 micro-tile.
__global__ __launch_bounds__(256) void proj_gemm_k(
    const float* __restrict__ x,
    const float* __restrict__ Wsq, const float* __restrict__ Wsk,
    const float* __restrict__ Wrq, const float* __restrict__ Wrv,
    float* __restrict__ SQ, float* __restrict__ SK,
    float* __restrict__ RQ, float* __restrict__ V)
{
    __shared__ float As[16][132];   // A transposed: As[k][m]
    __shared__ float Bs[16][68];    // Bs[k][n]
    const int tid = threadIdx.x;
    const int tx = tid & 15, ty = tid >> 4;
    const int bn = blockIdx.x;   // 0..25 (64-col tiles)
    const int bm = blockIdx.y;   // 0..31 (128-row tiles)

    const float* W; int ldw, off;
    if (bn < 8)       { W = Wsq; ldw = 512; off = bn * 64; }
    else if (bn < 16) { W = Wsk; ldw = 512; off = (bn - 8) * 64; }
    else if (bn < 24) { W = Wrq; ldw = 512; off = (bn - 16) * 64; }
    else              { W = Wrv; ldw = 128; off = (bn - 24) * 64; }

    float acc[8][4];
#pragma unroll
    for (int i = 0; i < 8; ++i)
#pragma unroll
        for (int j = 0; j < 4; ++j) acc[i][j] = 0.f;

    for (int kt = 0; kt < KDIM / 16; ++kt) {
#pragma unroll
        for (int t = 0; t < 2; ++t) {
            int idx = tid + t * 256;
            int r = idx >> 2, c4 = (idx & 3) * 4;
            float4 a = *(const float4*)&x[(size_t)(bm * 128 + r) * KDIM + kt * 16 + c4];
            As[c4 + 0][r] = a.x; As[c4 + 1][r] = a.y;
            As[c4 + 2][r] = a.z; As[c4 + 3][r] = a.w;
        }
        {
            int kr = tid >> 4, c4 = (tid & 15) * 4;
            *(float4*)&Bs[kr][c4] = *(const float4*)&W[(size_t)(kt * 16 + kr) * ldw + off + c4];
        }
        __syncthreads();
#pragma unroll
        for (int kk = 0; kk < 16; ++kk) {
            float4 a0 = *(float4*)&As[kk][ty * 8];
            float4 a1 = *(float4*)&As[kk][ty * 8 + 4];
            float4 b0 = *(float4*)&Bs[kk][tx * 4];
            float av[8] = {a0.x, a0.y, a0.z, a0.w, a1.x, a1.y, a1.z, a1.w};
            float bv[4] = {b0.x, b0.y, b0.z, b0.w};
#pragma unroll
            for (int i = 0; i < 8; ++i)
#pragma unroll
                for (int j = 0; j < 4; ++j) acc[i][j] += av[i] * bv[j];
        }
        __syncthreads();
    }

    const int j0 = bn * 64 + tx * 4;
    const int g = j0 >> 9;           // 0:Wsq 1:Wsk 2:Wrq 3:Wrv
    const int within = j0 & 511;
#pragma unroll
    for (int i = 0; i < 8; ++i) {
        int m = bm * 128 + ty * 8 + i;
        int bb = m >> 11, ni = m & (NSEQ - 1);
        float4 v4 = make_float4(acc[i][0], acc[i][1], acc[i][2], acc[i][3]);
        float* dst;
        if (g == 3) {
            dst = &V[((size_t)bb * NSEQ + ni) * (NR * DH) + within];
        } else {
            int s = within >> 6, d = within & 63;
            float* base = (g == 0) ? SQ : ((g == 1) ? SK : RQ);
            dst = &base[(((size_t)bb * NS + s) * NSEQ + ni) * DH + d];
        }
        *(float4*)dst = v4;
    }
}

// ================= Kernel 2: flash attention + fused retrieval stage =================
// One block per (b, s, 64-row q tile). Online softmax over 32 K-tiles of 64.
// Vcat (128 wide) processed in two 64-col halves sharing the K LDS region.
// Epilogue: normalize -> rk = ret@Wrk -> r_sim -> 2-way softmax -> combine -> O1[b][n][s][d].
__global__ __launch_bounds__(256) void attn_fused_k(
    const float* __restrict__ SQ, const float* __restrict__ SK,
    const float* __restrict__ RQ, const float* __restrict__ V,
    const float* __restrict__ Wrk, float* __restrict__ O1)
{
    __shared__ float smem[13696];    // 54.8 KB
    float* sQ   = smem;              // [64][68]  Q^T, pre-scaled by d^-0.5
    float* sP   = smem + 4352;       // [64][68]  P^T
    float* sB   = smem + 8704;       // [64][68]  K^T / V-half / Wrk (union)
    float* sRed = smem + 13056;      // 512 partial dots + 128 r_attn

    const int tid = threadIdx.x;
    const int tx = tid & 15, ty = tid >> 4;
    const int qt = blockIdx.x;
    const int s  = blockIdx.y;
    const int b  = blockIdx.z;

    const float* Qg = SQ + (((size_t)b * NS + s) * NSEQ + qt * 64) * DH;
    const float* Kg = SK + (((size_t)b * NS + s) * NSEQ) * DH;
    const float* Vg = V  + ((size_t)b * NSEQ) * (NR * DH);

    // load Q tile transposed, fold in softmax scale
#pragma unroll
    for (int t = 0; t < 4; ++t) {
        int idx = tid + t * 256;
        int r = idx >> 4, c4 = (idx & 15) * 4;
        float4 q = *(const float4*)&Qg[(size_t)r * DH + c4];
        sQ[(c4 + 0) * 68 + r] = q.x * 0.125f;
        sQ[(c4 + 1) * 68 + r] = q.y * 0.125f;
        sQ[(c4 + 2) * 68 + r] = q.z * 0.125f;
        sQ[(c4 + 3) * 68 + r] = q.w * 0.125f;
    }

    float o[4][8];
    float m_[4], l_[4];
#pragma unroll
    for (int i = 0; i < 4; ++i) {
        m_[i] = -1e30f; l_[i] = 0.f;
#pragma unroll
        for (int j = 0; j < 8; ++j) o[i][j] = 0.f;
    }

    for (int kt = 0; kt < NSEQ / 64; ++kt) {
        // K tile -> sB transposed
#pragma unroll
        for (int t = 0; t < 4; ++t) {
            int idx = tid + t * 256;
            int r = idx >> 4, c4 = (idx & 15) * 4;
            float4 k4 = *(const float4*)&Kg[(size_t)(kt * 64 + r) * DH + c4];
            sB[(c4 + 0) * 68 + r] = k4.x;
            sB[(c4 + 1) * 68 + r] = k4.y;
            sB[(c4 + 2) * 68 + r] = k4.z;
            sB[(c4 + 3) * 68 + r] = k4.w;
        }
        __syncthreads();   // (1) K ready (covers sQ on first iter)

        float sv[4][4];
#pragma unroll
        for (int i = 0; i < 4; ++i)
#pragma unroll
            for (int j = 0; j < 4; ++j) sv[i][j] = 0.f;

#pragma unroll 16
        for (int d = 0; d < 64; ++d) {
            float4 qa = *(float4*)&sQ[d * 68 + ty * 4];
            float4 kb = *(float4*)&sB[d * 68 + tx * 4];
            float qv[4] = {qa.x, qa.y, qa.z, qa.w};
            float kv[4] = {kb.x, kb.y, kb.z, kb.w};
#pragma unroll
            for (int i = 0; i < 4; ++i)
#pragma unroll
                for (int j = 0; j < 4; ++j) sv[i][j] += qv[i] * kv[j];
        }

        // online softmax (row stats shared across the 16-lane tx group)
#pragma unroll
        for (int i = 0; i < 4; ++i) {
            float mx = fmaxf(fmaxf(sv[i][0], sv[i][1]), fmaxf(sv[i][2], sv[i][3]));
            mx = fmaxf(mx, __shfl_xor(mx, 1));
            mx = fmaxf(mx, __shfl_xor(mx, 2));
            mx = fmaxf(mx, __shfl_xor(mx, 4));
            mx = fmaxf(mx, __shfl_xor(mx, 8));
            float mnew = fmaxf(m_[i], mx);
            float alpha = __expf(m_[i] - mnew);
            float rs = 0.f;
#pragma unroll
            for (int j = 0; j < 4; ++j) {
                float p = __expf(sv[i][j] - mnew);
                sv[i][j] = p;
                rs += p;
            }
            rs += __shfl_xor(rs, 1);
            rs += __shfl_xor(rs, 2);
            rs += __shfl_xor(rs, 4);
            rs += __shfl_xor(rs, 8);
            l_[i] = l_[i] * alpha + rs;
            m_[i] = mnew;
#pragma unroll
            for (int j = 0; j < 8; ++j) o[i][j] *= alpha;
#pragma unroll
            for (int j = 0; j < 4; ++j)
                sP[(tx * 4 + j) * 68 + ty * 4 + i] = sv[i][j];
        }
        __syncthreads();   // (2) P ready, K reads done

#pragma unroll
        for (int h = 0; h < 2; ++h) {
            // V half -> sB (overwrites K)
#pragma unroll
            for (int t = 0; t < 4; ++t) {
                int idx = tid + t * 256;
                int r = idx >> 4, c4 = (idx & 15) * 4;
                *(float4*)&sB[r * 68 + c4] =
                    *(const float4*)&Vg[(size_t)(kt * 64 + r) * (NR * DH) + h * 64 + c4];
            }
            __syncthreads();   // V half ready
#pragma unroll 16
            for (int k = 0; k < 64; ++k) {
                float4 pa = *(float4*)&sP[k * 68 + ty * 4];
                float4 vb = *(float4*)&sB[k * 68 + tx * 4];
                float pv[4] = {pa.x, pa.y, pa.z, pa.w};
                float vv[4] = {vb.x, vb.y, vb.z, vb.w};
#pragma unroll
                for (int i = 0; i < 4; ++i)
#pragma unroll
                    for (int j = 0; j < 4; ++j)
                        o[i][h * 4 + j] += pv[i] * vv[j];
            }
            __syncthreads();   // V half reads done (loop-end barrier)
        }
    }

    // ---------- fused retrieval epilogue ----------
    float* Ol = smem;   // [64][133] normalized retrieved, overlays sQ+sP (dead)
#pragma unroll
    for (int i = 0; i < 4; ++i) {
        int row = ty * 4 + i;
        float inv = 1.f / l_[i];
#pragma unroll
        for (int j = 0; j < 4; ++j) {
            Ol[row * 133 + tx * 4 + j]      = o[i][j] * inv;
            Ol[row * 133 + 64 + tx * 4 + j] = o[i][4 + j] * inv;
        }
    }
    // Wrk -> sB (dead after last PV)
#pragma unroll
    for (int t = 0; t < 4; ++t) {
        int idx = tid + t * 256;
        int r = idx >> 4, c4 = (idx & 15) * 4;
        *(float4*)&sB[r * 68 + c4] = *(const float4*)&Wrk[(size_t)r * 64 + c4];
    }
    __syncthreads();

    // rk = ret @ Wrk and partial dots with rq; thread = (row, 16-dim part)
    {
        int row = tid & 63, part = tid >> 6;
        const float* rqg = RQ + ((((size_t)b * NS + s) * NSEQ) + qt * 64 + row) * DH + part * 16;
        float rq[16];
#pragma unroll
        for (int c = 0; c < 4; ++c) {
            float4 t4 = *(const float4*)&rqg[c * 4];
            rq[c * 4 + 0] = t4.x; rq[c * 4 + 1] = t4.y;
            rq[c * 4 + 2] = t4.z; rq[c * 4 + 3] = t4.w;
        }
        float rk0[16], rk1[16];
#pragma unroll
        for (int e = 0; e < 16; ++e) { rk0[e] = 0.f; rk1[e] = 0.f; }
#pragma unroll 8
        for (int d = 0; d < 64; ++d) {
            float v0 = Ol[row * 133 + d];
            float v1 = Ol[row * 133 + 64 + d];
#pragma unroll
            for (int e = 0; e < 16; ++e) {
                float w = sB[d * 68 + part * 16 + e];
                rk0[e] += v0 * w;
                rk1[e] += v1 * w;
            }
        }
        float s0 = 0.f, s1 = 0.f;
#pragma unroll
        for (int e = 0; e < 16; ++e) { s0 += rq[e] * rk0[e]; s1 += rq[e] * rk1[e]; }
        sRed[(0 * 64 + row) * 4 + part] = s0;
        sRed[(1 * 64 + row) * 4 + part] = s1;
    }
    __syncthreads();

    float* ra = sRed + 512;
    if (tid < 64) {
        int row = tid;
        float r0 = (sRed[row * 4] + sRed[row * 4 + 1] +
                    sRed[row * 4 + 2] + sRed[row * 4 + 3]) * 0.125f;
        float r1 = (sRed[(64 + row) * 4] + sRed[(64 + row) * 4 + 1] +
                    sRed[(64 + row) * 4 + 2] + sRed[(64 + row) * 4 + 3]) * 0.125f;
        float mm = fmaxf(r0, r1);
        float e0 = __expf(r0 - mm), e1 = __expf(r1 - mm);
        float inv = 1.f / (e0 + e1);
        ra[row] = e0 * inv;
        ra[64 + row] = e1 * inv;
    }
    __syncthreads();

    // combine over r and store O1[b][n][s][d]
    {
        int row = tid >> 2, q4 = tid & 3;
        float a0 = ra[row], a1 = ra[64 + row];
        float* dst = O1 + (((size_t)b * NSEQ + qt * 64 + row) * NS + s) * DH + q4 * 16;
#pragma unroll
        for (int c = 0; c < 4; ++c) {
            int base0 = row * 133 + q4 * 16 + c * 4;
            float4 v4;
            v4.x = a0 * Ol[base0 + 0] + a1 * Ol[base0 + 64];
            v4.y = a0 * Ol[base0 + 1] + a1 * Ol[base0 + 65];
            v4.z = a0 * Ol[base0 + 2] + a1 * Ol[base0 + 66];
            v4.w = a0 * Ol[base0 + 3] + a1 * Ol[base0 + 67];
            *(float4*)&dst[c * 4] = v4;
        }
    }
}

// ================= Kernel 3: output GEMM =================
// C[4096 x 1024] = O1[4096 x 512] @ Wout[512 x 1024]
__global__ __launch_bounds__(256) void out_gemm_k(
    const float* __restrict__ A, const float* __restrict__ B, float* __restrict__ C)
{
    __shared__ float As[16][132];
    __shared__ float Bs[16][68];
    const int tid = threadIdx.x;
    const int tx = tid & 15, ty = tid >> 4;
    const int bn = blockIdx.x;   // 0..15
    const int bm = blockIdx.y;   // 0..31
    const int KD = NS * DH;      // 512

    float acc[8][4];
#pragma unroll
    for (int i = 0; i < 8; ++i)
#pragma unroll
        for (int j = 0; j < 4; ++j) acc[i][j] = 0.f;

    for (int kt = 0; kt < KD / 16; ++kt) {
#pragma unroll
        for (int t = 0; t < 2; ++t) {
            int idx = tid + t * 256;
            int r = idx >> 2, c4 = (idx & 3) * 4;
            float4 a = *(const float4*)&A[(size_t)(bm * 128 + r) * KD + kt * 16 + c4];
            As[c4 + 0][r] = a.x; As[c4 + 1][r] = a.y;
            As[c4 + 2][r] = a.z; As[c4 + 3][r] = a.w;
        }
        {
            int kr = tid >> 4, c4 = (tid & 15) * 4;
            *(float4*)&Bs[kr][c4] = *(const float4*)&B[(size_t)(kt * 16 + kr) * KDIM + bn * 64 + c4];
        }
        __syncthreads();
#pragma unroll
        for (int kk = 0; kk < 16; ++kk) {
            float4 a0 = *(float4*)&As[kk][ty * 8];
            float4 a1 = *(float4*)&As[kk][ty * 8 + 4];
            float4 b0 = *(float4*)&Bs[kk][tx * 4];
            float av[8] = {a0.x, a0.y, a0.z, a0.w, a1.x, a1.y, a1.z, a1.w};
            float bv[4] = {b0.x, b0.y, b0.z, b0.w};
#pragma unroll
            for (int i = 0; i < 8; ++i)
#pragma unroll
                for (int j = 0; j < 4; ++j) acc[i][j] += av[i] * bv[j];
        }
        __syncthreads();
    }

#pragma unroll
    for (int i = 0; i < 8; ++i) {
        int m = bm * 128 + ty * 8 + i;
        *(float4*)&C[(size_t)m * KDIM + bn * 64 + tx * 4] =
            make_float4(acc[i][0], acc[i][1], acc[i][2], acc[i][3]);
    }
}

extern "C" void kernel_launch(void* const* d_in, const int* in_sizes, int n_in,
                              void* d_out, int out_size, void* d_ws, size_t ws_size,
                              hipStream_t stream)
{
    const float* x    = (const float*)d_in[0];
    const float* Wsq  = (const float*)d_in[1];
    const float* Wsk  = (const float*)d_in[2];
    const float* Wrv  = (const float*)d_in[3];   // NOTE: Wrv before Wrq in input order
    const float* Wrq  = (const float*)d_in[4];
    const float* Wrk  = (const float*)d_in[5];
    const float* Wout = (const float*)d_in[6];
    float* out = (float*)d_out;
    float* ws  = (float*)d_ws;

    // workspace layout (floats): total 8,912,896 (~35.7 MB)
    float* SQ = ws;                                   // [2][8][2048][64]
    float* SK = SQ + (size_t)2 * NS * NSEQ * DH;      // [2][8][2048][64]
    float* RQ = SK + (size_t)2 * NS * NSEQ * DH;      // [2][8][2048][64]
    float* V  = RQ + (size_t)2 * NS * NSEQ * DH;      // [2][2048][128] (vcat)
    float* O1 = V  + (size_t)2 * NSEQ * NR * DH;      // [2][2048][8][64]

    proj_gemm_k<<<dim3(26, 32), 256, 0, stream>>>(x, Wsq, Wsk, Wrq, Wrv, SQ, SK, RQ, V);
    attn_fused_k<<<dim3(NSEQ / 64, NS, 2), 256, 0, stream>>>(SQ, SK, RQ, V, Wrk, O1);
    out_gemm_k<<<dim3(16, 32), 256, 0, stream>>>(O1, Wout, out);
}

// Round 2
// 399.013 us; speedup vs baseline: 1.6839x; 1.6839x over previous
//
#include <hip/hip_runtime.h>

#define NSEQ 2048
#define KDIM 1024
#define DH   64
#define NS   8
#define NR   2

typedef short bf16x8 __attribute__((ext_vector_type(8)));
typedef float f32x4  __attribute__((ext_vector_type(4)));

// may-alias access types: LDS regions are reused across phases with different
// element types; these keep the compiler's memory-dependence analysis honest
// (the P-write -> A-read path within a wave has NO barrier).
typedef unsigned short ushort_ma __attribute__((may_alias));
typedef bf16x8         bf16x8_ma __attribute__((may_alias));
typedef uint4          uint4_ma  __attribute__((may_alias));
typedef float4         float4_ma __attribute__((may_alias));

__device__ __forceinline__ unsigned short f2bf(float f) {
    unsigned int u = __builtin_bit_cast(unsigned int, f);
    u = (u + 0x7FFFu + ((u >> 16) & 1u)) >> 16;   // RTN-even
    return (unsigned short)u;
}
__device__ __forceinline__ float bf2f(unsigned short h) {
    unsigned int u = ((unsigned int)h) << 16;
    return __builtin_bit_cast(float, u);
}

// ================= Kernel 1: fused projection GEMM =================
// C[4096 x 1664] = x @ concat(Wsq, Wsk, Wrq, Wrv), scattered to:
//   Qb  bf16 [b][s][n][64]  (x0.125 folded)
//   Kb  bf16 [b][s][n][64]
//   RQ  f32  [b][s][n][64]
//   Vt  bf16 [b][128][2048]  (transposed V-cat)
__global__ __launch_bounds__(256) void proj_gemm_k(
    const float* __restrict__ x,
    const float* __restrict__ Wsq, const float* __restrict__ Wsk,
    const float* __restrict__ Wrq, const float* __restrict__ Wrv,
    unsigned short* __restrict__ Qb, unsigned short* __restrict__ Kb,
    float* __restrict__ RQ, unsigned short* __restrict__ Vt)
{
    __shared__ float As[16][132];
    __shared__ float Bs[16][68];
    const int tid = threadIdx.x;
    const int tx = tid & 15, ty = tid >> 4;
    const int bn = blockIdx.x;   // 0..25
    const int bm = blockIdx.y;   // 0..31

    const float* W; int ldw, off;
    if (bn < 8)       { W = Wsq; ldw = 512; off = bn * 64; }
    else if (bn < 16) { W = Wsk; ldw = 512; off = (bn - 8) * 64; }
    else if (bn < 24) { W = Wrq; ldw = 512; off = (bn - 16) * 64; }
    else              { W = Wrv; ldw = 128; off = (bn - 24) * 64; }

    float acc[8][4];
#pragma unroll
    for (int i = 0; i < 8; ++i)
#pragma unroll
        for (int j = 0; j < 4; ++j) acc[i][j] = 0.f;

    for (int kt = 0; kt < KDIM / 16; ++kt) {
#pragma unroll
        for (int t = 0; t < 2; ++t) {
            int idx = tid + t * 256;
            int r = idx >> 2, c4 = (idx & 3) * 4;
            float4 a = *(const float4*)&x[(size_t)(bm * 128 + r) * KDIM + kt * 16 + c4];
            As[c4 + 0][r] = a.x; As[c4 + 1][r] = a.y;
            As[c4 + 2][r] = a.z; As[c4 + 3][r] = a.w;
        }
        {
            int kr = tid >> 4, c4 = (tid & 15) * 4;
            *(float4*)&Bs[kr][c4] = *(const float4*)&W[(size_t)(kt * 16 + kr) * ldw + off + c4];
        }
        __syncthreads();
#pragma unroll
        for (int kk = 0; kk < 16; ++kk) {
            float4 a0 = *(float4*)&As[kk][ty * 8];
            float4 a1 = *(float4*)&As[kk][ty * 8 + 4];
            float4 b0 = *(float4*)&Bs[kk][tx * 4];
            float av[8] = {a0.x, a0.y, a0.z, a0.w, a1.x, a1.y, a1.z, a1.w};
            float bv[4] = {b0.x, b0.y, b0.z, b0.w};
#pragma unroll
            for (int i = 0; i < 8; ++i)
#pragma unroll
                for (int j = 0; j < 4; ++j) acc[i][j] += av[i] * bv[j];
        }
        __syncthreads();
    }

    const int j0 = bn * 64 + tx * 4;
    const int g = j0 >> 9;
    if (g == 3) {
        // V: write transposed bf16 Vt[b][d][n], 8 consecutive n per store
        int d0 = j0 & 127;
        int m0 = bm * 128 + ty * 8;
        int bb = m0 >> 11, n0 = m0 & (NSEQ - 1);
#pragma unroll
        for (int j = 0; j < 4; ++j) {
            uint4 w;
            w.x = (unsigned)f2bf(acc[0][j]) | ((unsigned)f2bf(acc[1][j]) << 16);
            w.y = (unsigned)f2bf(acc[2][j]) | ((unsigned)f2bf(acc[3][j]) << 16);
            w.z = (unsigned)f2bf(acc[4][j]) | ((unsigned)f2bf(acc[5][j]) << 16);
            w.w = (unsigned)f2bf(acc[6][j]) | ((unsigned)f2bf(acc[7][j]) << 16);
            *(uint4_ma*)&Vt[((size_t)bb * 128 + d0 + j) * NSEQ + n0] = w;
        }
    } else if (g == 2) {
        int within = j0 & 511;
        int s = within >> 6, d = within & 63;
#pragma unroll
        for (int i = 0; i < 8; ++i) {
            int m = bm * 128 + ty * 8 + i;
            int bb = m >> 11, ni = m & (NSEQ - 1);
            *(float4*)&RQ[(((size_t)bb * NS + s) * NSEQ + ni) * DH + d] =
                make_float4(acc[i][0], acc[i][1], acc[i][2], acc[i][3]);
        }
    } else {
        int within = j0 & 511;
        int s = within >> 6, d = within & 63;
        float sc = (g == 0) ? 0.125f : 1.0f;
        unsigned short* base = (g == 0) ? Qb : Kb;
#pragma unroll
        for (int i = 0; i < 8; ++i) {
            int m = bm * 128 + ty * 8 + i;
            int bb = m >> 11, ni = m & (NSEQ - 1);
            ushort4 h;
            h.x = f2bf(acc[i][0] * sc); h.y = f2bf(acc[i][1] * sc);
            h.z = f2bf(acc[i][2] * sc); h.w = f2bf(acc[i][3] * sc);
            *(ushort4*)&base[(((size_t)bb * NS + s) * NSEQ + ni) * DH + d] = h;
        }
    }
}

// ================= Kernel 2: MFMA flash attention + fused retrieval =================
// Block: 256 thr (4 waves), one (b, s, 64-q-row tile). Wave w owns q rows [w*16, w*16+16).
// LDS (40960 B): sQ[64][64]bf16 @0 | sK[64][64]bf16 @8192 | sVt[128][64]bf16 @16384
//                | sP 4x[16][64]bf16 @32768.  All row-swizzled: byte ^= ((row&7)<<4).
// Epilogue reuses: Ol 4x[16][128]bf16 @wid*4096, sWrk[64][64]f32 @16384.
__global__ __launch_bounds__(256) void attn_mfma_k(
    const unsigned short* __restrict__ Qb, const unsigned short* __restrict__ Kb,
    const unsigned short* __restrict__ Vt, const float* __restrict__ RQ,
    const float* __restrict__ Wrk, float* __restrict__ O1)
{
    __shared__ __align__(16) char smem[40960];
    const int tid = threadIdx.x;
    const int qt = blockIdx.x, s = blockIdx.y, b = blockIdx.z;
    const int wid = tid >> 6, lane = tid & 63;
    const int lrow = lane & 15, lgrp = lane >> 4;

    const unsigned short* Qg = Qb + (((size_t)(b * NS + s)) * NSEQ + qt * 64) * DH;
    const unsigned short* Kg = Kb + (((size_t)(b * NS + s)) * NSEQ) * DH;
    const unsigned short* Vg = Vt + (size_t)b * 128 * NSEQ;

    // stage Q (once), swizzled
#pragma unroll
    for (int t = 0; t < 2; ++t) {
        int c = tid + t * 256;
        int r = c >> 3, cc = c & 7;
        uint4 v = *(const uint4_ma*)(Qg + r * 64 + cc * 8);
        *(uint4_ma*)(smem + ((r * 128 + cc * 16) ^ ((r & 7) << 4))) = v;
    }

    f32x4 oacc[8];
#pragma unroll
    for (int df = 0; df < 8; ++df) oacc[df] = (f32x4){0.f, 0.f, 0.f, 0.f};
    float m_[4] = {-1e30f, -1e30f, -1e30f, -1e30f};
    float l_[4] = {0.f, 0.f, 0.f, 0.f};

    for (int kt = 0; kt < NSEQ / 64; ++kt) {
        __syncthreads();   // previous iter's K/V reads done (also fences Q stage)
        // stage K tile
#pragma unroll
        for (int t = 0; t < 2; ++t) {
            int c = tid + t * 256;
            int r = c >> 3, cc = c & 7;
            uint4 v = *(const uint4_ma*)(Kg + (size_t)(kt * 64 + r) * DH + cc * 8);
            *(uint4_ma*)(smem + 8192 + ((r * 128 + cc * 16) ^ ((r & 7) << 4))) = v;
        }
        // stage Vt tile [128 d][64 kv]
#pragma unroll
        for (int t = 0; t < 4; ++t) {
            int c = tid + t * 256;
            int d = c >> 3, cc = c & 7;
            uint4 v = *(const uint4_ma*)(Vg + (size_t)d * NSEQ + kt * 64 + cc * 8);
            *(uint4_ma*)(smem + 16384 + ((d * 128 + cc * 16) ^ ((d & 7) << 4))) = v;
        }
        __syncthreads();

        // ---- QK^T: S_w[16 q][64 kv] ----
        f32x4 sacc[4];
#pragma unroll
        for (int nf = 0; nf < 4; ++nf) sacc[nf] = (f32x4){0.f, 0.f, 0.f, 0.f};
#pragma unroll
        for (int kk = 0; kk < 2; ++kk) {
            int arow = wid * 16 + lrow;
            bf16x8 af = *(bf16x8_ma*)(smem + ((arow * 128 + kk * 64 + lgrp * 16) ^ ((arow & 7) << 4)));
#pragma unroll
            for (int nf = 0; nf < 4; ++nf) {
                int brow = nf * 16 + lrow;
                bf16x8 bf_ = *(bf16x8_ma*)(smem + 8192 + ((brow * 128 + kk * 64 + lgrp * 16) ^ ((brow & 7) << 4)));
                sacc[nf] = __builtin_amdgcn_mfma_f32_16x16x32_bf16(af, bf_, sacc[nf], 0, 0, 0);
            }
        }

        // ---- online softmax (per q-row r; stats shared across 16-lane group) ----
#pragma unroll
        for (int r = 0; r < 4; ++r) {
            float mx = fmaxf(fmaxf(sacc[0][r], sacc[1][r]), fmaxf(sacc[2][r], sacc[3][r]));
            mx = fmaxf(mx, __shfl_xor(mx, 1));
            mx = fmaxf(mx, __shfl_xor(mx, 2));
            mx = fmaxf(mx, __shfl_xor(mx, 4));
            mx = fmaxf(mx, __shfl_xor(mx, 8));
            float mnew = fmaxf(m_[r], mx);
            float alpha = __expf(m_[r] - mnew);
            float rs = 0.f;
            unsigned short pb[4];
#pragma unroll
            for (int f = 0; f < 4; ++f) {
                float p = __expf(sacc[f][r] - mnew);
                rs += p;
                pb[f] = f2bf(p);
            }
            rs += __shfl_xor(rs, 1);
            rs += __shfl_xor(rs, 2);
            rs += __shfl_xor(rs, 4);
            rs += __shfl_xor(rs, 8);
            l_[r] = l_[r] * alpha + rs;
            m_[r] = mnew;
#pragma unroll
            for (int df = 0; df < 8; ++df) oacc[df][r] *= alpha;
            int q = lgrp * 4 + r;   // local q row; P element (q, kv = lrow+16f)
#pragma unroll
            for (int f = 0; f < 4; ++f)
                *(ushort_ma*)(smem + 32768 + wid * 2048 +
                              ((q * 128 + (lrow + 16 * f) * 2) ^ ((q & 7) << 4))) = pb[f];
        }

        // ---- PV: O_w += P_w[16,64] x V[64,128]  (sP wave-local: no barrier) ----
#pragma unroll
        for (int kk = 0; kk < 2; ++kk) {
            bf16x8 pa = *(bf16x8_ma*)(smem + 32768 + wid * 2048 +
                                      ((lrow * 128 + kk * 64 + lgrp * 16) ^ ((lrow & 7) << 4)));
#pragma unroll
            for (int df = 0; df < 8; ++df) {
                int vrow = df * 16 + lrow;
                bf16x8 vb = *(bf16x8_ma*)(smem + 16384 +
                                          ((vrow * 128 + kk * 64 + lgrp * 16) ^ ((vrow & 7) << 4)));
                oacc[df] = __builtin_amdgcn_mfma_f32_16x16x32_bf16(pa, vb, oacc[df], 0, 0, 0);
            }
        }
    }

    // ================= fused retrieval epilogue =================
    __syncthreads();   // all sQ/sK/sVt reads done; regions reusable

    // normalized retrieved -> Ol bf16 [16][128] per wave (swizzled rows)
    float inv[4];
#pragma unroll
    for (int r = 0; r < 4; ++r) inv[r] = 1.f / l_[r];
    char* OlW = smem + wid * 4096;
#pragma unroll
    for (int r = 0; r < 4; ++r) {
        int q = lgrp * 4 + r;
#pragma unroll
        for (int df = 0; df < 8; ++df) {
            int d = df * 16 + lrow;
            *(ushort_ma*)(OlW + ((q * 256 + d * 2) ^ ((q & 7) << 4))) = f2bf(oacc[df][r] * inv[r]);
        }
    }
    // stage Wrk f32 [64][64] at +16384
#pragma unroll
    for (int t = 0; t < 4; ++t) {
        int c = tid + t * 256;
        int e = c >> 4, dd = (c & 15) * 4;
        *(float4_ma*)(smem + 16384 + e * 256 + dd * 4) = *(const float4_ma*)(Wrk + e * 64 + dd);
    }
    __syncthreads();

    {
        int row = lrow;          // q within wave tile
        int part = lgrp;         // 16-wide d_out slice
        int n = qt * 64 + wid * 16 + row;
        const float* rqg = RQ + ((((size_t)(b * NS + s)) * NSEQ) + n) * DH + part * 16;
        float rq[16];
#pragma unroll
        for (int c4 = 0; c4 < 4; ++c4) {
            float4 t4 = *(const float4_ma*)(rqg + c4 * 4);
            rq[c4 * 4 + 0] = t4.x; rq[c4 * 4 + 1] = t4.y;
            rq[c4 * 4 + 2] = t4.z; rq[c4 * 4 + 3] = t4.w;
        }
        float rk0[16], rk1[16];
#pragma unroll
        for (int j = 0; j < 16; ++j) { rk0[j] = 0.f; rk1[j] = 0.f; }
        const int rswz = (row & 7) << 4;
        for (int e = 0; e < 64; ++e) {
            float v0 = bf2f(*(ushort_ma*)(OlW + ((row * 256 + e * 2) ^ rswz)));
            float v1 = bf2f(*(ushort_ma*)(OlW + ((row * 256 + 128 + e * 2) ^ rswz)));
            const char* wr = smem + 16384 + e * 256 + part * 64;
            float4 w0 = *(const float4_ma*)(wr);
            float4 w1 = *(const float4_ma*)(wr + 16);
            float4 w2 = *(const float4_ma*)(wr + 32);
            float4 w3 = *(const float4_ma*)(wr + 48);
            float wv[16] = {w0.x, w0.y, w0.z, w0.w, w1.x, w1.y, w1.z, w1.w,
                            w2.x, w2.y, w2.z, w2.w, w3.x, w3.y, w3.z, w3.w};
#pragma unroll
            for (int j = 0; j < 16; ++j) {
                rk0[j] += v0 * wv[j];
                rk1[j] += v1 * wv[j];
            }
        }
        float s0 = 0.f, s1 = 0.f;
#pragma unroll
        for (int j = 0; j < 16; ++j) { s0 += rq[j] * rk0[j]; s1 += rq[j] * rk1[j]; }
        s0 += __shfl_xor(s0, 16); s0 += __shfl_xor(s0, 32);
        s1 += __shfl_xor(s1, 16); s1 += __shfl_xor(s1, 32);
        float r0 = s0 * 0.125f, r1 = s1 * 0.125f;
        float mm = fmaxf(r0, r1);
        float e0 = __expf(r0 - mm), e1 = __expf(r1 - mm);
        float rinv = 1.f / (e0 + e1);
        float a0 = e0 * rinv, a1 = e1 * rinv;

        float* dst = O1 + (((size_t)b * NSEQ + n) * NS + s) * DH + part * 16;
#pragma unroll
        for (int c4 = 0; c4 < 4; ++c4) {
            float4 o4;
            float t[4];
#pragma unroll
            for (int k = 0; k < 4; ++k) {
                int d = part * 16 + c4 * 4 + k;
                float v0 = bf2f(*(ushort_ma*)(OlW + ((row * 256 + d * 2) ^ rswz)));
                float v1 = bf2f(*(ushort_ma*)(OlW + ((row * 256 + (64 + d) * 2) ^ rswz)));
                t[k] = a0 * v0 + a1 * v1;
            }
            o4.x = t[0]; o4.y = t[1]; o4.z = t[2]; o4.w = t[3];
            *(float4_ma*)(dst + c4 * 4) = o4;
        }
    }
}

// ================= Kernel 3: output GEMM =================
__global__ __launch_bounds__(256) void out_gemm_k(
    const float* __restrict__ A, const float* __restrict__ B, float* __restrict__ C)
{
    __shared__ float As[16][132];
    __shared__ float Bs[16][68];
    const int tid = threadIdx.x;
    const int tx = tid & 15, ty = tid >> 4;
    const int bn = blockIdx.x;
    const int bm = blockIdx.y;
    const int KD = NS * DH;

    float acc[8][4];
#pragma unroll
    for (int i = 0; i < 8; ++i)
#pragma unroll
        for (int j = 0; j < 4; ++j) acc[i][j] = 0.f;

    for (int kt = 0; kt < KD / 16; ++kt) {
#pragma unroll
        for (int t = 0; t < 2; ++t) {
            int idx = tid + t * 256;
            int r = idx >> 2, c4 = (idx & 3) * 4;
            float4 a = *(const float4*)&A[(size_t)(bm * 128 + r) * KD + kt * 16 + c4];
            As[c4 + 0][r] = a.x; As[c4 + 1][r] = a.y;
            As[c4 + 2][r] = a.z; As[c4 + 3][r] = a.w;
        }
        {
            int kr = tid >> 4, c4 = (tid & 15) * 4;
            *(float4*)&Bs[kr][c4] = *(const float4*)&B[(size_t)(kt * 16 + kr) * KDIM + bn * 64 + c4];
        }
        __syncthreads();
#pragma unroll
        for (int kk = 0; kk < 16; ++kk) {
            float4 a0 = *(float4*)&As[kk][ty * 8];
            float4 a1 = *(float4*)&As[kk][ty * 8 + 4];
            float4 b0 = *(float4*)&Bs[kk][tx * 4];
            float av[8] = {a0.x, a0.y, a0.z, a0.w, a1.x, a1.y, a1.z, a1.w};
            float bv[4] = {b0.x, b0.y, b0.z, b0.w};
#pragma unroll
            for (int i = 0; i < 8; ++i)
#pragma unroll
                for (int j = 0; j < 4; ++j) acc[i][j] += av[i] * bv[j];
        }
        __syncthreads();
    }

#pragma unroll
    for (int i = 0; i < 8; ++i) {
        int m = bm * 128 + ty * 8 + i;
        *(float4*)&C[(size_t)m * KDIM + bn * 64 + tx * 4] =
            make_float4(acc[i][0], acc[i][1], acc[i][2], acc[i][3]);
    }
}

extern "C" void kernel_launch(void* const* d_in, const int* in_sizes, int n_in,
                              void* d_out, int out_size, void* d_ws, size_t ws_size,
                              hipStream_t stream)
{
    const float* x    = (const float*)d_in[0];
    const float* Wsq  = (const float*)d_in[1];
    const float* Wsk  = (const float*)d_in[2];
    const float* Wrv  = (const float*)d_in[3];
    const float* Wrq  = (const float*)d_in[4];
    const float* Wrk  = (const float*)d_in[5];
    const float* Wout = (const float*)d_in[6];
    float* out = (float*)d_out;

    // workspace layout: f32 first (alignment), then bf16
    float* RQ = (float*)d_ws;                                 // [2][8][2048][64] f32 (8 MB)
    float* O1 = RQ + (size_t)2 * NS * NSEQ * DH;              // [2][2048][8][64] f32 (8 MB)
    unsigned short* Qb = (unsigned short*)(O1 + (size_t)2 * NSEQ * NS * DH);  // (4 MB)
    unsigned short* Kb = Qb + (size_t)2 * NS * NSEQ * DH;     // (4 MB)
    unsigned short* Vtb = Kb + (size_t)2 * NS * NSEQ * DH;    // [2][128][2048] (1 MB)

    proj_gemm_k<<<dim3(26, 32), 256, 0, stream>>>(x, Wsq, Wsk, Wrq, Wrv, Qb, Kb, RQ, Vtb);
    attn_mfma_k<<<dim3(NSEQ / 64, NS, 2), 256, 0, stream>>>(Qb, Kb, Vtb, RQ, Wrk, O1);
    out_gemm_k<<<dim3(16, 32), 256, 0, stream>>>(O1, Wout, out);
}

// Round 3
// 205.963 us; speedup vs baseline: 3.2622x; 1.9373x over previous
//
#include <hip/hip_runtime.h>

#define NSEQ 2048
#define KDIM 1024
#define DH   64
#define NS   8
#define NR   2

typedef short bf16x8 __attribute__((ext_vector_type(8)));
typedef float f32x4  __attribute__((ext_vector_type(4)));

typedef unsigned short ushort_ma __attribute__((may_alias));
typedef bf16x8         bf16x8_ma __attribute__((may_alias));
typedef uint4          uint4_ma  __attribute__((may_alias));
typedef float4         float4_ma __attribute__((may_alias));

__device__ __forceinline__ unsigned short f2bf(float f) {
    unsigned int u = __builtin_bit_cast(unsigned int, f);
    u = (u + 0x7FFFu + ((u >> 16) & 1u)) >> 16;   // RTN-even
    return (unsigned short)u;
}
__device__ __forceinline__ float bf2f(unsigned short h) {
    unsigned int u = ((unsigned int)h) << 16;
    return __builtin_bit_cast(float, u);
}

// ============ prep 1: weight transpose + f32->bf16 ============
// Wt[1664][1024] = [0.125*Wsq | Wsk | Wrq | Wrv]^T   (bf16, B-operand layout [n][k])
// Wot[1024][512] = Wout^T                            (bf16)
__global__ __launch_bounds__(256) void prep_w_k(
    const float* __restrict__ Wsq, const float* __restrict__ Wsk,
    const float* __restrict__ Wrq, const float* __restrict__ Wrv,
    const float* __restrict__ Wout,
    unsigned short* __restrict__ Wt, unsigned short* __restrict__ Wot)
{
    __shared__ float sT[64][65];
    const int tid = threadIdx.x;
    const int bid = blockIdx.x;

    const float* src; int ldw, k0, n0, scol, ldo;
    unsigned short* dst;
    float sc = 1.0f;
    if (bid < 416) {
        int kt = bid / 26, nt = bid % 26;
        k0 = kt * 64; n0 = nt * 64;
        if (n0 < 512)       { src = Wsq; ldw = 512; scol = n0;        sc = 0.125f; }
        else if (n0 < 1024) { src = Wsk; ldw = 512; scol = n0 - 512;  }
        else if (n0 < 1536) { src = Wrq; ldw = 512; scol = n0 - 1024; }
        else                { src = Wrv; ldw = 128; scol = n0 - 1536; }
        dst = Wt; ldo = KDIM;
    } else {
        int r = bid - 416;
        int kt = r >> 4, nt = r & 15;
        k0 = kt * 64; n0 = nt * 64; scol = n0;
        src = Wout; ldw = KDIM;
        dst = Wot; ldo = 512;
    }

#pragma unroll
    for (int p = 0; p < 4; ++p) {
        int row = (tid >> 4) + p * 16;
        int col = (tid & 15) * 4;
        float4 v = *(const float4*)&src[(size_t)(k0 + row) * ldw + scol + col];
        sT[row][col + 0] = v.x; sT[row][col + 1] = v.y;
        sT[row][col + 2] = v.z; sT[row][col + 3] = v.w;
    }
    __syncthreads();

    {
        int n_l = tid >> 2, kg = (tid & 3) * 16;
        unsigned int w[8];
#pragma unroll
        for (int j = 0; j < 8; ++j) {
            unsigned short a = f2bf(sT[kg + 2 * j][n_l] * sc);
            unsigned short b = f2bf(sT[kg + 2 * j + 1][n_l] * sc);
            w[j] = (unsigned)a | ((unsigned)b << 16);
        }
        unsigned short* o = dst + (size_t)(n0 + n_l) * ldo + k0 + kg;
        *(uint4_ma*)o       = make_uint4(w[0], w[1], w[2], w[3]);
        *(uint4_ma*)(o + 8) = make_uint4(w[4], w[5], w[6], w[7]);
    }
}

// ============ prep 2: x -> bf16 hi/lo planes ============
__global__ __launch_bounds__(256) void prep_x_k(
    const float* __restrict__ x,
    unsigned short* __restrict__ xh, unsigned short* __restrict__ xl)
{
    const int total = 4096 * KDIM / 4;
    int idx = blockIdx.x * 256 + threadIdx.x;
    for (int i = idx; i < total; i += gridDim.x * 256) {
        float4 v = ((const float4_ma*)x)[i];
        ushort4 h, l;
        h.x = f2bf(v.x); l.x = f2bf(v.x - bf2f(h.x));
        h.y = f2bf(v.y); l.y = f2bf(v.y - bf2f(h.y));
        h.z = f2bf(v.z); l.z = f2bf(v.z - bf2f(h.z));
        h.w = f2bf(v.w); l.w = f2bf(v.w - bf2f(h.w));
        ((ushort4*)xh)[i] = h;
        ((ushort4*)xl)[i] = l;
    }
}

// ============ Kernel 1: projection GEMM (bf16 MFMA, split-x) ============
// C[4096 x 1664] = (xh+xl)[4096 x 1024] @ Wt^T, scattered to Qb/Kb/RQ/Vt.
// BM=128 BN=64 BK=64, 4 waves (2x2), 16x16x32 MFMA.
// LDS 40KB: Ah[128][64]bf16 @0 | Al @16384 | Bt[64][64]bf16 @32768, rows ^((r&7)<<4).
__global__ __launch_bounds__(256) void proj_mfma_k(
    const unsigned short* __restrict__ xh, const unsigned short* __restrict__ xl,
    const unsigned short* __restrict__ Wt,
    unsigned short* __restrict__ Qb, unsigned short* __restrict__ Kb,
    float* __restrict__ RQ, unsigned short* __restrict__ Vt)
{
    __shared__ __align__(16) char smem[40960];
    const int tid = threadIdx.x;
    const int bn = blockIdx.x, bm = blockIdx.y;
    const int wid = tid >> 6, lane = tid & 63;
    const int wm = wid >> 1, wn = wid & 1;
    const int lrow = lane & 15, lgrp = lane >> 4;

    f32x4 acc[4][2];
#pragma unroll
    for (int i = 0; i < 4; ++i)
#pragma unroll
        for (int j = 0; j < 2; ++j) acc[i][j] = (f32x4){0.f, 0.f, 0.f, 0.f};

    for (int kt = 0; kt < KDIM / 64; ++kt) {
        __syncthreads();
#pragma unroll
        for (int p = 0; p < 4; ++p) {
            int c = tid + p * 256;
            int r = c >> 3, cc = c & 7;
            int off = (r * 128 + cc * 16) ^ ((r & 7) << 4);
            size_t g = (size_t)(bm * 128 + r) * KDIM + kt * 64 + cc * 8;
            *(uint4_ma*)(smem + off)         = *(const uint4_ma*)(xh + g);
            *(uint4_ma*)(smem + 16384 + off) = *(const uint4_ma*)(xl + g);
        }
#pragma unroll
        for (int p = 0; p < 2; ++p) {
            int c = tid + p * 256;
            int r = c >> 3, cc = c & 7;
            *(uint4_ma*)(smem + 32768 + ((r * 128 + cc * 16) ^ ((r & 7) << 4))) =
                *(const uint4_ma*)(Wt + (size_t)(bn * 64 + r) * KDIM + kt * 64 + cc * 8);
        }
        __syncthreads();
#pragma unroll
        for (int ks = 0; ks < 2; ++ks) {
            bf16x8 bfr[2];
#pragma unroll
            for (int nf = 0; nf < 2; ++nf) {
                int rb = wn * 32 + nf * 16 + lrow;
                bfr[nf] = *(bf16x8_ma*)(smem + 32768 + ((rb * 128 + ks * 64 + lgrp * 16) ^ ((rb & 7) << 4)));
            }
#pragma unroll
            for (int mf = 0; mf < 4; ++mf) {
                int ra = wm * 64 + mf * 16 + lrow;
                int offa = (ra * 128 + ks * 64 + lgrp * 16) ^ ((ra & 7) << 4);
                bf16x8 ah = *(bf16x8_ma*)(smem + offa);
                bf16x8 al = *(bf16x8_ma*)(smem + 16384 + offa);
#pragma unroll
                for (int nf = 0; nf < 2; ++nf) {
                    acc[mf][nf] = __builtin_amdgcn_mfma_f32_16x16x32_bf16(ah, bfr[nf], acc[mf][nf], 0, 0, 0);
                    acc[mf][nf] = __builtin_amdgcn_mfma_f32_16x16x32_bf16(al, bfr[nf], acc[mf][nf], 0, 0, 0);
                }
            }
        }
    }

    const int g = bn >> 3;   // 0:Q 1:K 2:RQ 3:V
#pragma unroll
    for (int mf = 0; mf < 4; ++mf) {
#pragma unroll
        for (int nf = 0; nf < 2; ++nf) {
            int j0 = bn * 64 + wn * 32 + nf * 16 + lrow;
            int m0 = bm * 128 + wm * 64 + mf * 16 + lgrp * 4;
            if (g == 3) {
                int dv = j0 - 1536;
                int bb = m0 >> 11, seq = m0 & (NSEQ - 1);
                ushort4 h;
                h.x = f2bf(acc[mf][nf][0]); h.y = f2bf(acc[mf][nf][1]);
                h.z = f2bf(acc[mf][nf][2]); h.w = f2bf(acc[mf][nf][3]);
                *(ushort4*)&Vt[((size_t)bb * 128 + dv) * NSEQ + seq] = h;
            } else {
                int s = (j0 >> 6) & 7, d = j0 & 63;
#pragma unroll
                for (int r = 0; r < 4; ++r) {
                    int m = m0 + r;
                    int bb = m >> 11, seq = m & (NSEQ - 1);
                    size_t idx = (((size_t)(bb * NS + s)) * NSEQ + seq) * DH + d;
                    if (g == 2)      RQ[idx] = acc[mf][nf][r];
                    else if (g == 0) Qb[idx] = f2bf(acc[mf][nf][r]);
                    else             Kb[idx] = f2bf(acc[mf][nf][r]);
                }
            }
        }
    }
}

// ============ Kernel 2: MFMA flash attention + fused retrieval ============
__global__ __launch_bounds__(256) void attn_mfma_k(
    const unsigned short* __restrict__ Qb, const unsigned short* __restrict__ Kb,
    const unsigned short* __restrict__ Vt, const float* __restrict__ RQ,
    const float* __restrict__ Wrk, unsigned short* __restrict__ O1b)
{
    __shared__ __align__(16) char smem[40960];
    const int tid = threadIdx.x;
    const int qt = blockIdx.x, s = blockIdx.y, b = blockIdx.z;
    const int wid = tid >> 6, lane = tid & 63;
    const int lrow = lane & 15, lgrp = lane >> 4;

    const unsigned short* Qg = Qb + (((size_t)(b * NS + s)) * NSEQ + qt * 64) * DH;
    const unsigned short* Kg = Kb + (((size_t)(b * NS + s)) * NSEQ) * DH;
    const unsigned short* Vg = Vt + (size_t)b * 128 * NSEQ;

#pragma unroll
    for (int t = 0; t < 2; ++t) {
        int c = tid + t * 256;
        int r = c >> 3, cc = c & 7;
        uint4 v = *(const uint4_ma*)(Qg + r * 64 + cc * 8);
        *(uint4_ma*)(smem + ((r * 128 + cc * 16) ^ ((r & 7) << 4))) = v;
    }

    f32x4 oacc[8];
#pragma unroll
    for (int df = 0; df < 8; ++df) oacc[df] = (f32x4){0.f, 0.f, 0.f, 0.f};
    float m_[4] = {-1e30f, -1e30f, -1e30f, -1e30f};
    float l_[4] = {0.f, 0.f, 0.f, 0.f};

    for (int kt = 0; kt < NSEQ / 64; ++kt) {
        __syncthreads();
#pragma unroll
        for (int t = 0; t < 2; ++t) {
            int c = tid + t * 256;
            int r = c >> 3, cc = c & 7;
            uint4 v = *(const uint4_ma*)(Kg + (size_t)(kt * 64 + r) * DH + cc * 8);
            *(uint4_ma*)(smem + 8192 + ((r * 128 + cc * 16) ^ ((r & 7) << 4))) = v;
        }
#pragma unroll
        for (int t = 0; t < 4; ++t) {
            int c = tid + t * 256;
            int d = c >> 3, cc = c & 7;
            uint4 v = *(const uint4_ma*)(Vg + (size_t)d * NSEQ + kt * 64 + cc * 8);
            *(uint4_ma*)(smem + 16384 + ((d * 128 + cc * 16) ^ ((d & 7) << 4))) = v;
        }
        __syncthreads();

        f32x4 sacc[4];
#pragma unroll
        for (int nf = 0; nf < 4; ++nf) sacc[nf] = (f32x4){0.f, 0.f, 0.f, 0.f};
#pragma unroll
        for (int kk = 0; kk < 2; ++kk) {
            int arow = wid * 16 + lrow;
            bf16x8 af = *(bf16x8_ma*)(smem + ((arow * 128 + kk * 64 + lgrp * 16) ^ ((arow & 7) << 4)));
#pragma unroll
            for (int nf = 0; nf < 4; ++nf) {
                int brow = nf * 16 + lrow;
                bf16x8 bf_ = *(bf16x8_ma*)(smem + 8192 + ((brow * 128 + kk * 64 + lgrp * 16) ^ ((brow & 7) << 4)));
                sacc[nf] = __builtin_amdgcn_mfma_f32_16x16x32_bf16(af, bf_, sacc[nf], 0, 0, 0);
            }
        }

#pragma unroll
        for (int r = 0; r < 4; ++r) {
            float mx = fmaxf(fmaxf(sacc[0][r], sacc[1][r]), fmaxf(sacc[2][r], sacc[3][r]));
            mx = fmaxf(mx, __shfl_xor(mx, 1));
            mx = fmaxf(mx, __shfl_xor(mx, 2));
            mx = fmaxf(mx, __shfl_xor(mx, 4));
            mx = fmaxf(mx, __shfl_xor(mx, 8));
            float mnew = fmaxf(m_[r], mx);
            float alpha = __expf(m_[r] - mnew);
            float rs = 0.f;
            unsigned short pb[4];
#pragma unroll
            for (int f = 0; f < 4; ++f) {
                float p = __expf(sacc[f][r] - mnew);
                rs += p;
                pb[f] = f2bf(p);
            }
            rs += __shfl_xor(rs, 1);
            rs += __shfl_xor(rs, 2);
            rs += __shfl_xor(rs, 4);
            rs += __shfl_xor(rs, 8);
            l_[r] = l_[r] * alpha + rs;
            m_[r] = mnew;
#pragma unroll
            for (int df = 0; df < 8; ++df) oacc[df][r] *= alpha;
            int q = lgrp * 4 + r;
#pragma unroll
            for (int f = 0; f < 4; ++f)
                *(ushort_ma*)(smem + 32768 + wid * 2048 +
                              ((q * 128 + (lrow + 16 * f) * 2) ^ ((q & 7) << 4))) = pb[f];
        }

#pragma unroll
        for (int kk = 0; kk < 2; ++kk) {
            bf16x8 pa = *(bf16x8_ma*)(smem + 32768 + wid * 2048 +
                                      ((lrow * 128 + kk * 64 + lgrp * 16) ^ ((lrow & 7) << 4)));
#pragma unroll
            for (int df = 0; df < 8; ++df) {
                int vrow = df * 16 + lrow;
                bf16x8 vb = *(bf16x8_ma*)(smem + 16384 +
                                          ((vrow * 128 + kk * 64 + lgrp * 16) ^ ((vrow & 7) << 4)));
                oacc[df] = __builtin_amdgcn_mfma_f32_16x16x32_bf16(pa, vb, oacc[df], 0, 0, 0);
            }
        }
    }

    __syncthreads();

    float inv[4];
#pragma unroll
    for (int r = 0; r < 4; ++r) inv[r] = 1.f / l_[r];
    char* OlW = smem + wid * 4096;
#pragma unroll
    for (int r = 0; r < 4; ++r) {
        int q = lgrp * 4 + r;
#pragma unroll
        for (int df = 0; df < 8; ++df) {
            int d = df * 16 + lrow;
            *(ushort_ma*)(OlW + ((q * 256 + d * 2) ^ ((q & 7) << 4))) = f2bf(oacc[df][r] * inv[r]);
        }
    }
#pragma unroll
    for (int t = 0; t < 4; ++t) {
        int c = tid + t * 256;
        int e = c >> 4, dd = (c & 15) * 4;
        *(float4_ma*)(smem + 16384 + e * 256 + dd * 4) = *(const float4_ma*)(Wrk + e * 64 + dd);
    }
    __syncthreads();

    {
        int row = lrow;
        int part = lgrp;
        int n = qt * 64 + wid * 16 + row;
        const float* rqg = RQ + ((((size_t)(b * NS + s)) * NSEQ) + n) * DH + part * 16;
        float rq[16];
#pragma unroll
        for (int c4 = 0; c4 < 4; ++c4) {
            float4 t4 = *(const float4_ma*)(rqg + c4 * 4);
            rq[c4 * 4 + 0] = t4.x; rq[c4 * 4 + 1] = t4.y;
            rq[c4 * 4 + 2] = t4.z; rq[c4 * 4 + 3] = t4.w;
        }
        float rk0[16], rk1[16];
#pragma unroll
        for (int j = 0; j < 16; ++j) { rk0[j] = 0.f; rk1[j] = 0.f; }
        const int rswz = (row & 7) << 4;
        for (int e = 0; e < 64; ++e) {
            float v0 = bf2f(*(ushort_ma*)(OlW + ((row * 256 + e * 2) ^ rswz)));
            float v1 = bf2f(*(ushort_ma*)(OlW + ((row * 256 + 128 + e * 2) ^ rswz)));
            const char* wr = smem + 16384 + e * 256 + part * 64;
            float4 w0 = *(const float4_ma*)(wr);
            float4 w1 = *(const float4_ma*)(wr + 16);
            float4 w2 = *(const float4_ma*)(wr + 32);
            float4 w3 = *(const float4_ma*)(wr + 48);
            float wv[16] = {w0.x, w0.y, w0.z, w0.w, w1.x, w1.y, w1.z, w1.w,
                            w2.x, w2.y, w2.z, w2.w, w3.x, w3.y, w3.z, w3.w};
#pragma unroll
            for (int j = 0; j < 16; ++j) {
                rk0[j] += v0 * wv[j];
                rk1[j] += v1 * wv[j];
            }
        }
        float s0 = 0.f, s1 = 0.f;
#pragma unroll
        for (int j = 0; j < 16; ++j) { s0 += rq[j] * rk0[j]; s1 += rq[j] * rk1[j]; }
        s0 += __shfl_xor(s0, 16); s0 += __shfl_xor(s0, 32);
        s1 += __shfl_xor(s1, 16); s1 += __shfl_xor(s1, 32);
        float r0 = s0 * 0.125f, r1 = s1 * 0.125f;
        float mm = fmaxf(r0, r1);
        float e0 = __expf(r0 - mm), e1 = __expf(r1 - mm);
        float rinv = 1.f / (e0 + e1);
        float a0 = e0 * rinv, a1 = e1 * rinv;

        unsigned short* dst = O1b + ((size_t)(b * NSEQ + n)) * (NS * DH) + s * DH + part * 16;
#pragma unroll
        for (int c4 = 0; c4 < 4; ++c4) {
            ushort4 o4;
            float t[4];
#pragma unroll
            for (int k = 0; k < 4; ++k) {
                int d = part * 16 + c4 * 4 + k;
                float v0 = bf2f(*(ushort_ma*)(OlW + ((row * 256 + d * 2) ^ rswz)));
                float v1 = bf2f(*(ushort_ma*)(OlW + ((row * 256 + (64 + d) * 2) ^ rswz)));
                t[k] = a0 * v0 + a1 * v1;
            }
            o4.x = f2bf(t[0]); o4.y = f2bf(t[1]); o4.z = f2bf(t[2]); o4.w = f2bf(t[3]);
            *(ushort4*)(dst + c4 * 4) = o4;
        }
    }
}

// ============ Kernel 3: output GEMM (bf16 MFMA) ============
// out[4096 x 1024] = O1b[4096 x 512] @ Wot^T
// BM=128 BN=64 BK=64, LDS 24KB: A[128][64] @0 | B[64][64] @16384.
__global__ __launch_bounds__(256) void out_mfma_k(
    const unsigned short* __restrict__ A, const unsigned short* __restrict__ Bw,
    float* __restrict__ C)
{
    __shared__ __align__(16) char smem[24576];
    const int tid = threadIdx.x;
    const int bn = blockIdx.x, bm = blockIdx.y;
    const int wid = tid >> 6, lane = tid & 63;
    const int wm = wid >> 1, wn = wid & 1;
    const int lrow = lane & 15, lgrp = lane >> 4;
    const int KD = NS * DH;   // 512

    f32x4 acc[4][2];
#pragma unroll
    for (int i = 0; i < 4; ++i)
#pragma unroll
        for (int j = 0; j < 2; ++j) acc[i][j] = (f32x4){0.f, 0.f, 0.f, 0.f};

    for (int kt = 0; kt < KD / 64; ++kt) {
        __syncthreads();
#pragma unroll
        for (int p = 0; p < 4; ++p) {
            int c = tid + p * 256;
            int r = c >> 3, cc = c & 7;
            *(uint4_ma*)(smem + ((r * 128 + cc * 16) ^ ((r & 7) << 4))) =
                *(const uint4_ma*)(A + (size_t)(bm * 128 + r) * KD + kt * 64 + cc * 8);
        }
#pragma unroll
        for (int p = 0; p < 2; ++p) {
            int c = tid + p * 256;
            int r = c >> 3, cc = c & 7;
            *(uint4_ma*)(smem + 16384 + ((r * 128 + cc * 16) ^ ((r & 7) << 4))) =
                *(const uint4_ma*)(Bw + (size_t)(bn * 64 + r) * KD + kt * 64 + cc * 8);
        }
        __syncthreads();
#pragma unroll
        for (int ks = 0; ks < 2; ++ks) {
            bf16x8 bfr[2];
#pragma unroll
            for (int nf = 0; nf < 2; ++nf) {
                int rb = wn * 32 + nf * 16 + lrow;
                bfr[nf] = *(bf16x8_ma*)(smem + 16384 + ((rb * 128 + ks * 64 + lgrp * 16) ^ ((rb & 7) << 4)));
            }
#pragma unroll
            for (int mf = 0; mf < 4; ++mf) {
                int ra = wm * 64 + mf * 16 + lrow;
                bf16x8 af = *(bf16x8_ma*)(smem + ((ra * 128 + ks * 64 + lgrp * 16) ^ ((ra & 7) << 4)));
#pragma unroll
                for (int nf = 0; nf < 2; ++nf)
                    acc[mf][nf] = __builtin_amdgcn_mfma_f32_16x16x32_bf16(af, bfr[nf], acc[mf][nf], 0, 0, 0);
            }
        }
    }

#pragma unroll
    for (int mf = 0; mf < 4; ++mf) {
#pragma unroll
        for (int nf = 0; nf < 2; ++nf) {
            int j0 = bn * 64 + wn * 32 + nf * 16 + lrow;
            int m0 = bm * 128 + wm * 64 + mf * 16 + lgrp * 4;
#pragma unroll
            for (int r = 0; r < 4; ++r)
                C[(size_t)(m0 + r) * KDIM + j0] = acc[mf][nf][r];
        }
    }
}

extern "C" void kernel_launch(void* const* d_in, const int* in_sizes, int n_in,
                              void* d_out, int out_size, void* d_ws, size_t ws_size,
                              hipStream_t stream)
{
    const float* x    = (const float*)d_in[0];
    const float* Wsq  = (const float*)d_in[1];
    const float* Wsk  = (const float*)d_in[2];
    const float* Wrv  = (const float*)d_in[3];
    const float* Wrq  = (const float*)d_in[4];
    const float* Wrk  = (const float*)d_in[5];
    const float* Wout = (const float*)d_in[6];
    float* out = (float*)d_out;

    // workspace layout (37.3 MB)
    float* RQ            = (float*)d_ws;                        // [2][8][2048][64] f32, 8 MB
    unsigned short* Wt   = (unsigned short*)(RQ + (size_t)2 * NS * NSEQ * DH);  // [1664][1024], 3.25 MB
    unsigned short* Wot  = Wt + (size_t)1664 * KDIM;            // [1024][512], 1 MB
    unsigned short* Qb   = Wot + (size_t)KDIM * 512;            // [2][8][2048][64], 4 MB
    unsigned short* Kb   = Qb + (size_t)2 * NS * NSEQ * DH;     // 4 MB
    unsigned short* Vtb  = Kb + (size_t)2 * NS * NSEQ * DH;     // [2][128][2048], 1 MB
    unsigned short* xh   = Vtb + (size_t)2 * 128 * NSEQ;        // [4096][1024], 8 MB
    unsigned short* xl   = xh + (size_t)4096 * KDIM;            // 8 MB
    unsigned short* O1b  = xh;  // alias: xh dead after proj_mfma_k

    prep_w_k<<<544, 256, 0, stream>>>(Wsq, Wsk, Wrq, Wrv, Wout, Wt, Wot);
    prep_x_k<<<2048, 256, 0, stream>>>(x, xh, xl);
    proj_mfma_k<<<dim3(26, 32), 256, 0, stream>>>(xh, xl, Wt, Qb, Kb, RQ, Vtb);
    attn_mfma_k<<<dim3(NSEQ / 64, NS, 2), 256, 0, stream>>>(Qb, Kb, Vtb, RQ, Wrk, O1b);
    out_mfma_k<<<dim3(16, 32), 256, 0, stream>>>(O1b, Wot, out);
}